// Round 3
// baseline (176.764 us; speedup 1.0000x reference)
//
#include <hip/hip_runtime.h>

// SSIM loss, fused single-pass.
// Reference: five 7x7 zero-padded box SUMS over {a, b, a*a, b*b, a*b},
// elementwise SSIM map, global mean, out = 1 - mean.
//
// Tile: 128 cols x 64 rows per 256-thread block (4 waves x 16 rows).
// Both raw tiles staged in LDS with halo (70 rows x 136 cols, float4-aligned
// staging). Each lane owns 2 output columns; per new row it reads the 8-float
// window union as 5 x ds_read_b64, builds the five horizontal 7-tap sums for
// both columns, and maintains vertical 7-row running sums via an 8-slot ring
// (fully unrolled -> all ring indices compile-time static, no scratch).
// Wave shuffle reduce -> block sum -> one double atomicAdd -> finalize.

constexpr int IMG = 512;
constexpr int TW = 128;                 // tile width (output cols)
constexpr int TH = 64;                  // tile height (output rows)
constexpr int LROWS = TH + 6;           // 70 staged rows (vert halo 3+3)
constexpr int PITCH = 136;              // staged floats/row (halo 4 left, 4 right)
constexpr int F4_PER_ROW = PITCH / 4;   // 34
constexpr int NSTAGE = LROWS * F4_PER_ROW;  // 2380 float4 chunks per image
constexpr float C1 = 1.0e-4f;           // 0.01^2
constexpr float C2 = 9.0e-4f;           // 0.03^2
constexpr double INV_N = 1.0 / (64.0 * 512.0 * 512.0);

__global__ __launch_bounds__(256, 2)
void ssim_fused(const float* __restrict__ img1, const float* __restrict__ img2,
                double* __restrict__ partial) {
    __shared__ float sa[LROWS][PITCH];   // 38,080 B
    __shared__ float sb[LROWS][PITCH];   // 38,080 B  (total 76,176 B -> 2 blocks/CU)
    __shared__ float wpart[4];

    const int tid = threadIdx.x;
    const int tx0 = blockIdx.x * TW;
    const int ty0 = blockIdx.y * TH;
    const size_t ib = (size_t)blockIdx.z * (IMG * IMG);
    const float* b1 = img1 + ib;
    const float* b2 = img2 + ib;

    // ---- stage both tiles, float4 chunks, zero outside image ----
    // LDS col c <-> gx = tx0 - 4 + c ; chunks are 16B aligned in global
    // (tx0 % 4 == 0) and never straddle the x-boundary (512 % 4 == 0).
    for (int idx = tid; idx < NSTAGE; idx += 256) {
        int r = idx / F4_PER_ROW;            // magic-mul div (const divisor)
        int c4 = idx - r * F4_PER_ROW;
        int gy = ty0 - 3 + r;
        int gx = tx0 - 4 + 4 * c4;
        float4 va = make_float4(0.f, 0.f, 0.f, 0.f);
        float4 vb = make_float4(0.f, 0.f, 0.f, 0.f);
        if ((unsigned)gy < (unsigned)IMG && (unsigned)gx < (unsigned)IMG) {
            int g = gy * IMG + gx;
            va = *(const float4*)(b1 + g);
            vb = *(const float4*)(b2 + g);
        }
        *(float4*)&sa[r][4 * c4] = va;
        *(float4*)&sb[r][4 * c4] = vb;
    }
    __syncthreads();

    // ---- per-wave band: lane owns cols (2l, 2l+1); rows [seg*16, seg*16+16) ----
    const int l = tid & 63;
    const int seg = tid >> 6;
    const int y0 = seg * 16;        // first output row (tile-rel); window LDS rows y..y+6
    const int cb = 2 * l;           // LDS float col of v[0]; windows use v[1..7], v[2..8]

    // 8-slot rings: 5 quantities x 2 columns
    float rA0[8], rA1[8], rB0[8], rB1[8], rAA0[8], rAA1[8],
          rBB0[8], rBB1[8], rAB0[8], rAB1[8];
    float SA0 = 0, SA1 = 0, SB0 = 0, SB1 = 0, SAA0 = 0, SAA1 = 0,
          SBB0 = 0, SBB1 = 0, SAB0 = 0, SAB1 = 0;
    float acc = 0.f;

    // horizontal 7-tap sums for LDS row rr -> ring slot k (k static after unroll)
    auto hrow = [&](int rr, int k) {
        const float2* pa = (const float2*)&sa[rr][cb];   // 8B aligned
        const float2* pb = (const float2*)&sb[rr][cb];
        float2 a0 = pa[0], a1 = pa[1], a2 = pa[2], a3 = pa[3], a4 = pa[4];
        float2 b0 = pb[0], b1v = pb[1], b2v = pb[2], b3 = pb[3], b4 = pb[4];
        float va1 = a0.y, va2 = a1.x, va3 = a1.y, va4 = a2.x,
              va5 = a2.y, va6 = a3.x, va7 = a3.y, va8 = a4.x;
        float vb1 = b0.y, vb2 = b1v.x, vb3 = b1v.y, vb4 = b2v.x,
              vb5 = b2v.y, vb6 = b3.x, vb7 = b3.y, vb8 = b4.x;

        float sA = ((va1 + va2) + (va3 + va4)) + ((va5 + va6) + va7);
        rA0[k] = sA;
        rA1[k] = (sA - va1) + va8;

        float sB = ((vb1 + vb2) + (vb3 + vb4)) + ((vb5 + vb6) + vb7);
        rB0[k] = sB;
        rB1[k] = (sB - vb1) + vb8;

        float sAA = fmaf(va7, va7, fmaf(va6, va6, fmaf(va5, va5,
                    fmaf(va4, va4, fmaf(va3, va3, fmaf(va2, va2, va1 * va1))))));
        rAA0[k] = sAA;
        rAA1[k] = fmaf(va8, va8, sAA - va1 * va1);

        float sBB = fmaf(vb7, vb7, fmaf(vb6, vb6, fmaf(vb5, vb5,
                    fmaf(vb4, vb4, fmaf(vb3, vb3, fmaf(vb2, vb2, vb1 * vb1))))));
        rBB0[k] = sBB;
        rBB1[k] = fmaf(vb8, vb8, sBB - vb1 * vb1);

        float sAB = fmaf(va7, vb7, fmaf(va6, vb6, fmaf(va5, vb5,
                    fmaf(va4, vb4, fmaf(va3, vb3, fmaf(va2, vb2, va1 * vb1))))));
        rAB0[k] = sAB;
        rAB1[k] = fmaf(va8, vb8, sAB - va1 * vb1);
    };

    // prime ring with window rows y0 .. y0+5 (slots 0..5)
#pragma unroll
    for (int k = 0; k < 6; ++k) {
        hrow(y0 + k, k);
        SA0 += rA0[k]; SA1 += rA1[k]; SB0 += rB0[k]; SB1 += rB1[k];
        SAA0 += rAA0[k]; SAA1 += rAA1[k]; SBB0 += rBB0[k]; SBB1 += rBB1[k];
        SAB0 += rAB0[k]; SAB1 += rAB1[k];
    }

    // 16 output rows, fully unrolled (static ring indices)
#pragma unroll
    for (int t = 0; t < 16; ++t) {
        const int kn = (t + 6) & 7;   // incoming window row y0+t+6
        const int ko = t & 7;         // outgoing window row y0+t
        hrow(y0 + t + 6, kn);
        SA0 += rA0[kn]; SA1 += rA1[kn]; SB0 += rB0[kn]; SB1 += rB1[kn];
        SAA0 += rAA0[kn]; SAA1 += rAA1[kn]; SBB0 += rBB0[kn]; SBB1 += rBB1[kn];
        SAB0 += rAB0[kn]; SAB1 += rAB1[kn];

        {   // SSIM, col 2l
            float m12 = SA0 * SB0, m11 = SA0 * SA0, m22 = SB0 * SB0;
            float num = fmaf(2.f, m12, C1) * fmaf(2.f, SAB0 - m12, C2);
            float den = (m11 + m22 + C1) * ((SAA0 - m11) + (SBB0 - m22) + C2);
            acc += num / den;
        }
        {   // SSIM, col 2l+1
            float m12 = SA1 * SB1, m11 = SA1 * SA1, m22 = SB1 * SB1;
            float num = fmaf(2.f, m12, C1) * fmaf(2.f, SAB1 - m12, C2);
            float den = (m11 + m22 + C1) * ((SAA1 - m11) + (SBB1 - m22) + C2);
            acc += num / den;
        }

        SA0 -= rA0[ko]; SA1 -= rA1[ko]; SB0 -= rB0[ko]; SB1 -= rB1[ko];
        SAA0 -= rAA0[ko]; SAA1 -= rAA1[ko]; SBB0 -= rBB0[ko]; SBB1 -= rBB1[ko];
        SAB0 -= rAB0[ko]; SAB1 -= rAB1[ko];
    }

    // ---- reduce: wave shuffle -> LDS -> one double atomic per block ----
#pragma unroll
    for (int off = 32; off > 0; off >>= 1)
        acc += __shfl_xor(acc, off);
    if (l == 0) wpart[seg] = acc;
    __syncthreads();
    if (tid == 0)
        atomicAdd(partial, (double)((wpart[0] + wpart[1]) + (wpart[2] + wpart[3])));
}

__global__ void ssim_finalize(const double* __restrict__ partial,
                              float* __restrict__ out) {
    out[0] = (float)(1.0 - partial[0] * INV_N);
}

extern "C" void kernel_launch(void* const* d_in, const int* in_sizes, int n_in,
                              void* d_out, int out_size, void* d_ws, size_t ws_size,
                              hipStream_t stream) {
    const float* img1 = (const float*)d_in[0];
    const float* img2 = (const float*)d_in[1];
    float* out = (float*)d_out;
    double* partial = (double*)d_ws;

    hipMemsetAsync(partial, 0, sizeof(double), stream);

    dim3 grid(IMG / TW, IMG / TH, 64);   // 4 x 8 x 64 = 2048 blocks
    ssim_fused<<<grid, 256, 0, stream>>>(img1, img2, partial);
    ssim_finalize<<<1, 1, 0, stream>>>(partial, out);
}